// Round 1
// baseline (498.166 us; speedup 1.0000x reference)
//
#include <hip/hip_runtime.h>

typedef __bf16 bf16_t;
typedef __bf16 bf16x8 __attribute__((ext_vector_type(8)));
typedef float  f32x4  __attribute__((ext_vector_type(4)));

#define MFMA16(a, b, c) __builtin_amdgcn_mfma_f32_16x16x32_bf16((a), (b), (c), 0, 0, 0)

__device__ __forceinline__ void gload_lds16(const void* g, void* l) {
  __builtin_amdgcn_global_load_lds((__attribute__((address_space(1))) void*)(g),
                                   (__attribute__((address_space(3))) void*)(l),
                                   16, 0, 0);
}

// ---------------------------------------------------------------- convert
__global__ __launch_bounds__(256) void cvt_kernel(const float* __restrict__ in,
                                                  bf16_t* __restrict__ out, int n) {
  int i = (blockIdx.x * 256 + threadIdx.x) * 8;
  if (i >= n) return;
  const float4* p = reinterpret_cast<const float4*>(in + i);
  float4 a = p[0], b = p[1];
  bf16x8 v;
  v[0] = (bf16_t)a.x; v[1] = (bf16_t)a.y; v[2] = (bf16_t)a.z; v[3] = (bf16_t)a.w;
  v[4] = (bf16_t)b.x; v[5] = (bf16_t)b.y; v[6] = (bf16_t)b.z; v[7] = (bf16_t)b.w;
  *reinterpret_cast<bf16x8*>(out + i) = v;
}

// ---------------------------------------------------------------- GEMM  C[M,N] = A[M,K] * B[N,K]^T
// m97 structure: 128x128 tile, BK=64, 4 waves (2x2), global_load_lds w16,
// XOR-swizzled source (chunk' = chunk ^ (row&7)) so ds_read_b128 is ~2-way.
template <typename T>
__global__ __launch_bounds__(256) void gemm_bt(const bf16_t* __restrict__ A,
                                               const bf16_t* __restrict__ B,
                                               T* __restrict__ C,
                                               int M, int N, int K) {
  constexpr int BK = 64;
  int tid  = threadIdx.x;
  int lane = tid & 63, w = tid >> 6;
  int wr = w >> 1, wc = w & 1;
  int l15 = lane & 15, lhi = lane >> 4;
  int row0 = blockIdx.y * 128, col0 = blockIdx.x * 128;

  __shared__ alignas(16) char smem[128 * BK * 2 * 2];  // 16KB A + 16KB B
  char* sA = smem;
  char* sB = smem + 128 * BK * 2;

  f32x4 acc[4][4] = {};

  for (int k0 = 0; k0 < K; k0 += BK) {
#pragma unroll
    for (int i = 0; i < 4; ++i) {
      int c = i * 256 + tid;          // chunk id 0..1023 (16B chunks)
      int r = c >> 3, kc = c & 7;
      int kk = k0 + ((kc ^ (r & 7)) << 3);   // pre-swizzled global source
      gload_lds16(A + (size_t)(row0 + r) * K + kk, sA + c * 16);
      gload_lds16(B + (size_t)(col0 + r) * K + kk, sB + c * 16);
    }
    __syncthreads();
#pragma unroll
    for (int s = 0; s < 2; ++s) {
      bf16x8 af[4], bfr[4];
#pragma unroll
      for (int mi = 0; mi < 4; ++mi) {
        int r = wr * 64 + mi * 16 + l15;
        af[mi] = *reinterpret_cast<const bf16x8*>(
            sA + r * 128 + (((s * 4 + lhi) ^ (r & 7)) << 4));
      }
#pragma unroll
      for (int nj = 0; nj < 4; ++nj) {
        int r = wc * 64 + nj * 16 + l15;
        bfr[nj] = *reinterpret_cast<const bf16x8*>(
            sB + r * 128 + (((s * 4 + lhi) ^ (r & 7)) << 4));
      }
#pragma unroll
      for (int mi = 0; mi < 4; ++mi)
#pragma unroll
        for (int nj = 0; nj < 4; ++nj)
          acc[mi][nj] = MFMA16(af[mi], bfr[nj], acc[mi][nj]);
    }
    __syncthreads();
  }

#pragma unroll
  for (int mi = 0; mi < 4; ++mi)
#pragma unroll
    for (int nj = 0; nj < 4; ++nj)
#pragma unroll
      for (int r2 = 0; r2 < 4; ++r2) {
        int row = row0 + wr * 64 + mi * 16 + lhi * 4 + r2;
        int col = col0 + wc * 64 + nj * 16 + l15;
        C[(size_t)row * N + col] = (T)acc[mi][nj][r2];
      }
}

// ---------------------------------------------------------------- V transpose: qkv V-part -> Vt[256][4096]
__global__ __launch_bounds__(256) void transpose_v(const bf16_t* __restrict__ qkv,
                                                   bf16_t* __restrict__ vt) {
  __shared__ bf16_t tile[64][65];
  int t = threadIdx.x;
  int c = t & 63, r4 = t >> 6;
  int sb = blockIdx.x * 64, hb = blockIdx.y * 64;
#pragma unroll
  for (int i = 0; i < 16; ++i) {
    int r = i * 4 + r4;
    tile[r][c] = qkv[(size_t)(sb + r) * 1536 + 1280 + hb + c];
  }
  __syncthreads();
#pragma unroll
  for (int i = 0; i < 16; ++i) {
    int r = i * 4 + r4;
    vt[(size_t)(hb + r) * 4096 + sb + c] = tile[c][r];
  }
}

// ---------------------------------------------------------------- flash attention (causal GQA)
// grid (S/128, NH); 4 waves/block, wave-private: 32 q-rows/wave, KV-step 64.
__global__ __launch_bounds__(256) void attn_kernel(const bf16_t* __restrict__ qkv,
                                                   const bf16_t* __restrict__ vt,
                                                   bf16_t* __restrict__ ctx) {
  int tid = threadIdx.x, lane = tid & 63, w = tid >> 6;
  int l15 = lane & 15, lhi = lane >> 4;
  int h = blockIdx.y, g = h >> 2;
  int r0 = blockIdx.x * 128 + w * 32;

  __shared__ alignas(16) char pl_all[4][32 * 128];  // per-wave P buffer [32][64] bf16, swizzled
  char* pl = pl_all[w];

  bf16x8 qf[2][2];
#pragma unroll
  for (int mi = 0; mi < 2; ++mi)
#pragma unroll
    for (int ks = 0; ks < 2; ++ks)
      qf[mi][ks] = *reinterpret_cast<const bf16x8*>(
          qkv + (size_t)(r0 + mi * 16 + l15) * 1536 + h * 64 + ks * 32 + lhi * 8);

  f32x4 O[2][4] = {};
  float mS[2][4], lS[2][4];
#pragma unroll
  for (int mi = 0; mi < 2; ++mi)
#pragma unroll
    for (int r = 0; r < 4; ++r) { mS[mi][r] = -1e30f; lS[mi][r] = 0.f; }

  for (int j0 = 0; j0 < r0 + 32; j0 += 64) {
    f32x4 sfr[2][4];
#pragma unroll
    for (int nj = 0; nj < 4; ++nj) {
      const bf16_t* kp = qkv + (size_t)(j0 + nj * 16 + l15) * 1536 + 1024 + g * 64 + lhi * 8;
      bf16x8 kf0 = *reinterpret_cast<const bf16x8*>(kp);
      bf16x8 kf1 = *reinterpret_cast<const bf16x8*>(kp + 32);
#pragma unroll
      for (int mi = 0; mi < 2; ++mi) {
        f32x4 t = {0.f, 0.f, 0.f, 0.f};
        t = MFMA16(qf[mi][0], kf0, t);
        t = MFMA16(qf[mi][1], kf1, t);
        sfr[mi][nj] = t;
      }
    }
    bool domask = (j0 + 64 > r0);
#pragma unroll
    for (int mi = 0; mi < 2; ++mi)
#pragma unroll
      for (int nj = 0; nj < 4; ++nj)
#pragma unroll
        for (int r = 0; r < 4; ++r) {
          float sv = sfr[mi][nj][r] * 0.125f;
          if (domask) {
            int key  = j0 + nj * 16 + l15;
            int qrow = r0 + mi * 16 + lhi * 4 + r;
            if (key > qrow) sv = -1e30f;
          }
          sfr[mi][nj][r] = sv;
        }
    // online softmax per row (row lives in the 16 lanes of one lhi group)
#pragma unroll
    for (int mi = 0; mi < 2; ++mi)
#pragma unroll
      for (int r = 0; r < 4; ++r) {
        float mx = fmaxf(fmaxf(sfr[mi][0][r], sfr[mi][1][r]),
                         fmaxf(sfr[mi][2][r], sfr[mi][3][r]));
        mx = fmaxf(mx, __shfl_xor(mx, 1));
        mx = fmaxf(mx, __shfl_xor(mx, 2));
        mx = fmaxf(mx, __shfl_xor(mx, 4));
        mx = fmaxf(mx, __shfl_xor(mx, 8));
        float mnew  = fmaxf(mS[mi][r], mx);
        float alpha = exp2f((mS[mi][r] - mnew) * 1.44269504f);
        mS[mi][r] = mnew;
        float ps = 0.f;
#pragma unroll
        for (int nj = 0; nj < 4; ++nj) {
          float p = exp2f((sfr[mi][nj][r] - mnew) * 1.44269504f);
          sfr[mi][nj][r] = p;
          ps += p;
        }
        ps += __shfl_xor(ps, 1);
        ps += __shfl_xor(ps, 2);
        ps += __shfl_xor(ps, 4);
        ps += __shfl_xor(ps, 8);
        lS[mi][r] = lS[mi][r] * alpha + ps;
#pragma unroll
        for (int hd = 0; hd < 4; ++hd) O[mi][hd][r] *= alpha;
      }
    // P -> LDS (bf16, XOR-swizzled chunks: chunk' = (col>>3) ^ (row&7))
#pragma unroll
    for (int mi = 0; mi < 2; ++mi)
#pragma unroll
      for (int nj = 0; nj < 4; ++nj)
#pragma unroll
        for (int r = 0; r < 4; ++r) {
          int prow = mi * 16 + lhi * 4 + r;
          int col  = nj * 16 + l15;
          int sw   = (col >> 3) ^ (prow & 7);
          *reinterpret_cast<bf16_t*>(pl + prow * 128 + sw * 16 + (col & 7) * 2) =
              (bf16_t)sfr[mi][nj][r];
        }
    __threadfence_block();
    bf16x8 ap[2][2];
#pragma unroll
    for (int mi = 0; mi < 2; ++mi)
#pragma unroll
      for (int ks = 0; ks < 2; ++ks) {
        int prow = mi * 16 + l15;
        int ch   = (ks * 4 + lhi) ^ (prow & 7);
        ap[mi][ks] = *reinterpret_cast<const bf16x8*>(pl + prow * 128 + ch * 16);
      }
#pragma unroll
    for (int hd = 0; hd < 4; ++hd) {
      const bf16_t* vp = vt + (size_t)(g * 64 + hd * 16 + l15) * 4096 + j0 + lhi * 8;
      bf16x8 bv0 = *reinterpret_cast<const bf16x8*>(vp);
      bf16x8 bv1 = *reinterpret_cast<const bf16x8*>(vp + 32);
#pragma unroll
      for (int mi = 0; mi < 2; ++mi) {
        O[mi][hd] = MFMA16(ap[mi][0], bv0, O[mi][hd]);
        O[mi][hd] = MFMA16(ap[mi][1], bv1, O[mi][hd]);
      }
    }
    __threadfence_block();  // WAR fence before next iter's P writes
  }

#pragma unroll
  for (int mi = 0; mi < 2; ++mi)
#pragma unroll
    for (int hd = 0; hd < 4; ++hd)
#pragma unroll
      for (int r = 0; r < 4; ++r) {
        int row = r0 + mi * 16 + lhi * 4 + r;
        float v = O[mi][hd][r] / lS[mi][r];
        ctx[(size_t)row * 1024 + h * 64 + hd * 16 + l15] = (bf16_t)v;
      }
}

// ---------------------------------------------------------------- launch
extern "C" void kernel_launch(void* const* d_in, const int* in_sizes, int n_in,
                              void* d_out, int out_size, void* d_ws, size_t ws_size,
                              hipStream_t stream) {
  const float* x  = (const float*)d_in[0];
  const float* wq = (const float*)d_in[1];
  const float* wk = (const float*)d_in[2];
  const float* wv = (const float*)d_in[3];
  const float* wo = (const float*)d_in[4];
  float* out = (float*)d_out;

  char* ws = (char*)d_ws;
  size_t off = 0;
  auto alloc = [&](size_t b) {
    char* p = ws + off;
    off += (b + 255) & ~(size_t)255;
    return p;
  };
  bf16_t* xb   = (bf16_t*)alloc((size_t)4096 * 1024 * 2);
  bf16_t* wqkv = (bf16_t*)alloc((size_t)1536 * 1024 * 2);
  bf16_t* wob  = (bf16_t*)alloc((size_t)1024 * 1024 * 2);
  bf16_t* qkv  = (bf16_t*)alloc((size_t)4096 * 1536 * 2);
  bf16_t* vtb  = (bf16_t*)alloc((size_t)256 * 4096 * 2);
  bf16_t* ctx  = (bf16_t*)alloc((size_t)4096 * 1024 * 2);

  cvt_kernel<<<2048, 256, 0, stream>>>(x, xb, 4096 * 1024);
  cvt_kernel<<<512, 256, 0, stream>>>(wq, wqkv, 1024 * 1024);
  cvt_kernel<<<128, 256, 0, stream>>>(wk, wqkv + (size_t)1024 * 1024, 256 * 1024);
  cvt_kernel<<<128, 256, 0, stream>>>(wv, wqkv + (size_t)1280 * 1024, 256 * 1024);
  cvt_kernel<<<512, 256, 0, stream>>>(wo, wob, 1024 * 1024);

  gemm_bt<bf16_t><<<dim3(12, 32), 256, 0, stream>>>(xb, wqkv, qkv, 4096, 1536, 1024);
  transpose_v<<<dim3(64, 4), 256, 0, stream>>>(qkv, vtb);
  attn_kernel<<<dim3(32, 16), 256, 0, stream>>>(qkv, vtb, ctx);
  gemm_bt<float><<<dim3(8, 32), 256, 0, stream>>>(ctx, wob, out, 4096, 1024, 1024);
}

// Round 2
// 251.147 us; speedup vs baseline: 1.9836x; 1.9836x over previous
//
#include <hip/hip_runtime.h>

typedef __bf16 bf16_t;
typedef __bf16 bf16x8 __attribute__((ext_vector_type(8)));
typedef float  f32x4  __attribute__((ext_vector_type(4)));

#define MFMA16(a, b, c) __builtin_amdgcn_mfma_f32_16x16x32_bf16((a), (b), (c), 0, 0, 0)

__device__ __forceinline__ void gload_lds16(const void* g, void* l) {
  __builtin_amdgcn_global_load_lds((__attribute__((address_space(1))) void*)(g),
                                   (__attribute__((address_space(3))) void*)(l),
                                   16, 0, 0);
}

// ---------------------------------------------------------------- convert
__global__ __launch_bounds__(256) void cvt_kernel(const float* __restrict__ in,
                                                  bf16_t* __restrict__ out, int n) {
  int i = (blockIdx.x * 256 + threadIdx.x) * 8;
  if (i >= n) return;
  const float4* p = reinterpret_cast<const float4*>(in + i);
  float4 a = p[0], b = p[1];
  bf16x8 v;
  v[0] = (bf16_t)a.x; v[1] = (bf16_t)a.y; v[2] = (bf16_t)a.z; v[3] = (bf16_t)a.w;
  v[4] = (bf16_t)b.x; v[5] = (bf16_t)b.y; v[6] = (bf16_t)b.z; v[7] = (bf16_t)b.w;
  *reinterpret_cast<bf16x8*>(out + i) = v;
}

// ---------------------------------------------------------------- GEMM  C[M,N] = A[M,K] * B[N,K]^T
template <typename T>
__global__ __launch_bounds__(256) void gemm_bt(const bf16_t* __restrict__ A,
                                               const bf16_t* __restrict__ B,
                                               T* __restrict__ C,
                                               int M, int N, int K) {
  constexpr int BK = 64;
  int tid  = threadIdx.x;
  int lane = tid & 63, w = tid >> 6;
  int wr = w >> 1, wc = w & 1;
  int l15 = lane & 15, lhi = lane >> 4;
  int row0 = blockIdx.y * 128, col0 = blockIdx.x * 128;

  __shared__ alignas(16) char smem[128 * BK * 2 * 2];
  char* sA = smem;
  char* sB = smem + 128 * BK * 2;

  f32x4 acc[4][4] = {};

  for (int k0 = 0; k0 < K; k0 += BK) {
#pragma unroll
    for (int i = 0; i < 4; ++i) {
      int c = i * 256 + tid;
      int r = c >> 3, kc = c & 7;
      int kk = k0 + ((kc ^ (r & 7)) << 3);
      gload_lds16(A + (size_t)(row0 + r) * K + kk, sA + c * 16);
      gload_lds16(B + (size_t)(col0 + r) * K + kk, sB + c * 16);
    }
    __syncthreads();
#pragma unroll
    for (int s = 0; s < 2; ++s) {
      bf16x8 af[4], bfr[4];
#pragma unroll
      for (int mi = 0; mi < 4; ++mi) {
        int r = wr * 64 + mi * 16 + l15;
        af[mi] = *reinterpret_cast<const bf16x8*>(
            sA + r * 128 + (((s * 4 + lhi) ^ (r & 7)) << 4));
      }
#pragma unroll
      for (int nj = 0; nj < 4; ++nj) {
        int r = wc * 64 + nj * 16 + l15;
        bfr[nj] = *reinterpret_cast<const bf16x8*>(
            sB + r * 128 + (((s * 4 + lhi) ^ (r & 7)) << 4));
      }
#pragma unroll
      for (int mi = 0; mi < 4; ++mi)
#pragma unroll
        for (int nj = 0; nj < 4; ++nj)
          acc[mi][nj] = MFMA16(af[mi], bfr[nj], acc[mi][nj]);
    }
    __syncthreads();
  }

#pragma unroll
  for (int mi = 0; mi < 4; ++mi)
#pragma unroll
    for (int nj = 0; nj < 4; ++nj)
#pragma unroll
      for (int r2 = 0; r2 < 4; ++r2) {
        int row = row0 + wr * 64 + mi * 16 + lhi * 4 + r2;
        int col = col0 + wc * 64 + nj * 16 + l15;
        C[(size_t)row * N + col] = (T)acc[mi][nj][r2];
      }
}

// ---------------------------------------------------------------- V transpose: qkv V-part -> Vt[256][4096]
__global__ __launch_bounds__(256) void transpose_v(const bf16_t* __restrict__ qkv,
                                                   bf16_t* __restrict__ vt) {
  __shared__ bf16_t tile[64][65];
  int t = threadIdx.x;
  int c = t & 63, r4 = t >> 6;
  int sb = blockIdx.x * 64, hb = blockIdx.y * 64;
#pragma unroll
  for (int i = 0; i < 16; ++i) {
    int r = i * 4 + r4;
    tile[r][c] = qkv[(size_t)(sb + r) * 1536 + 1280 + hb + c];
  }
  __syncthreads();
#pragma unroll
  for (int i = 0; i < 16; ++i) {
    int r = i * 4 + r4;
    vt[(size_t)(hb + r) * 4096 + sb + c] = tile[c][r];
  }
}

// ---------------------------------------------------------------- flash attention (causal GQA)
// grid (32, 16): x -> q-tile (LPT reversed), y -> head. 4 waves x 32 rows.
// Shared double-buffered K/V LDS staging; swapped QK^T (S^T) softmax.
__global__ __launch_bounds__(256) void attn_kernel(const bf16_t* __restrict__ qkv,
                                                   const bf16_t* __restrict__ vt,
                                                   bf16_t* __restrict__ ctx) {
  int tid = threadIdx.x, lane = tid & 63, w = tid >> 6;
  int l15 = lane & 15, lhi = lane >> 4;
  int e = l15 & 7;
  int h = blockIdx.y, g = h >> 2;
  int tile = 31 - blockIdx.x;          // LPT: heavy tiles dispatched first
  int base = tile * 128;
  int r0 = base + w * 32;
  int nsteps = tile * 2 + 2;

  __shared__ alignas(16) char kbuf[2][8192];   // [64 keys][64 d] bf16, swizzled
  __shared__ alignas(16) char vbuf[2][8192];   // [64 hd][64 keys] bf16, swizzled
  __shared__ alignas(16) char pbuf_all[4][4096];  // per-wave P [32][64] bf16, swizzled
  __shared__ alignas(16) float albuf_all[4][32];
  char* pbuf = pbuf_all[w];
  float* albuf = albuf_all[w];

  // Q fragments (used as MFMA B-operand: col=qrow=l15, k-slice d=lhi*8)
  bf16x8 qf[2][2];
#pragma unroll
  for (int mi = 0; mi < 2; ++mi)
#pragma unroll
    for (int ks = 0; ks < 2; ++ks)
      qf[mi][ks] = *reinterpret_cast<const bf16x8*>(
          qkv + (size_t)(r0 + mi * 16 + l15) * 1536 + h * 64 + ks * 32 + lhi * 8);

  f32x4 O[2][4] = {};
  float mS[2] = {-1e30f, -1e30f}, lS[2] = {0.f, 0.f};
  const float SC = 0.125f * 1.44269504f;  // scale * log2(e), folded into exp2 args

  auto STAGE = [&](int s, int b) {
    int j0 = s * 64;
#pragma unroll
    for (int i = 0; i < 2; ++i) {
      int c = i * 256 + tid;          // 512 chunks of 16B per tile
      int r = c >> 3, sl = c & 7;
      int gk = (sl ^ (r & 7)) << 3;   // pre-swizzled global source column
      gload_lds16(qkv + (size_t)(j0 + r) * 1536 + 1024 + g * 64 + gk, &kbuf[b][c * 16]);
      gload_lds16(vt + (size_t)(g * 64 + r) * 4096 + j0 + gk, &vbuf[b][c * 16]);
    }
  };

  STAGE(0, 0);
  __syncthreads();   // compiler drains vmcnt before s_barrier

  for (int step = 0; step < nsteps; ++step) {
    int b = step & 1;
    if (step + 1 < nsteps) STAGE(step + 1, b ^ 1);
    int j0 = step * 64;
    if (j0 < r0 + 32) {   // wave-uniform activity predicate
      const char* kt  = kbuf[b];
      const char* vtl = vbuf[b];
      // ---- QK^T (swapped): st[nj][mi] has key=nj*16+lhi*4+r, qrow=mi*16+l15
      f32x4 st[4][2];
#pragma unroll
      for (int nj = 0; nj < 4; ++nj) {
        const char* krow = kt + (nj * 16 + l15) * 128;
        bf16x8 k0 = *reinterpret_cast<const bf16x8*>(krow + ((lhi ^ e) << 4));
        bf16x8 k1 = *reinterpret_cast<const bf16x8*>(krow + (((4 + lhi) ^ e) << 4));
#pragma unroll
        for (int mi = 0; mi < 2; ++mi) {
          f32x4 t = {0.f, 0.f, 0.f, 0.f};
          t = MFMA16(k0, qf[mi][0], t);
          t = MFMA16(k1, qf[mi][1], t);
          st[nj][mi] = t;
        }
      }
      // ---- causal mask (boundary steps only)
      if (j0 + 64 > r0) {
#pragma unroll
        for (int nj = 0; nj < 4; ++nj)
#pragma unroll
          for (int mi = 0; mi < 2; ++mi)
#pragma unroll
            for (int r = 0; r < 4; ++r) {
              int key = j0 + nj * 16 + lhi * 4 + r;
              int qr  = r0 + mi * 16 + l15;
              if (key > qr) st[nj][mi][r] = -1e30f;
            }
      }
      // ---- online softmax (row is lane-local: 16 vals in-reg + 2 shfls)
#pragma unroll
      for (int mi = 0; mi < 2; ++mi) {
        float mx = st[0][mi][0];
#pragma unroll
        for (int nj = 0; nj < 4; ++nj)
#pragma unroll
          for (int r = 0; r < 4; ++r)
            if (nj || r) mx = fmaxf(mx, st[nj][mi][r]);
        mx = fmaxf(mx, __shfl_xor(mx, 16));
        mx = fmaxf(mx, __shfl_xor(mx, 32));
        float mnew  = fmaxf(mS[mi], mx);
        float alpha = exp2f((mS[mi] - mnew) * SC);
        mS[mi] = mnew;
        float ps = 0.f;
#pragma unroll
        for (int nj = 0; nj < 4; ++nj)
#pragma unroll
          for (int r = 0; r < 4; ++r) {
            float p = exp2f((st[nj][mi][r] - mnew) * SC);
            st[nj][mi][r] = p;
            ps += p;
          }
        ps += __shfl_xor(ps, 16);
        ps += __shfl_xor(ps, 32);
        lS[mi] = lS[mi] * alpha + ps;
        if (lhi == 0) albuf[mi * 16 + l15] = alpha;
      }
      // ---- P -> LDS (bf16, swizzled [qrow][key])
#pragma unroll
      for (int mi = 0; mi < 2; ++mi) {
        char* prow = pbuf + (mi * 16 + l15) * 128 + ((lhi & 1) << 3);
#pragma unroll
        for (int nj = 0; nj < 4; ++nj) {
          int sw = (nj * 2 + (lhi >> 1)) ^ e;
          union { bf16_t hh[2]; uint32_t u; } a, c;
          a.hh[0] = (bf16_t)st[nj][mi][0]; a.hh[1] = (bf16_t)st[nj][mi][1];
          c.hh[0] = (bf16_t)st[nj][mi][2]; c.hh[1] = (bf16_t)st[nj][mi][3];
          *reinterpret_cast<uint32_t*>(prow + sw * 16)     = a.u;
          *reinterpret_cast<uint32_t*>(prow + sw * 16 + 4) = c.u;
        }
      }
      // ---- O rescale (alpha broadcast from LDS strip, O layout qrow=lhi*4+r)
#pragma unroll
      for (int mi = 0; mi < 2; ++mi) {
        f32x4 al = *reinterpret_cast<const f32x4*>(albuf + mi * 16 + lhi * 4);
#pragma unroll
        for (int h4 = 0; h4 < 4; ++h4)
#pragma unroll
          for (int r = 0; r < 4; ++r) O[mi][h4][r] *= al[r];
      }
      // ---- PV: A = P (qrow=l15), B = V^T (hd=l15)
      bf16x8 ap[2][2];
#pragma unroll
      for (int mi = 0; mi < 2; ++mi)
#pragma unroll
        for (int ks = 0; ks < 2; ++ks)
          ap[mi][ks] = *reinterpret_cast<const bf16x8*>(
              pbuf + (mi * 16 + l15) * 128 + (((ks * 4 + lhi) ^ e) << 4));
#pragma unroll
      for (int h4 = 0; h4 < 4; ++h4) {
        const char* vrow = vtl + (h4 * 16 + l15) * 128;
        bf16x8 v0 = *reinterpret_cast<const bf16x8*>(vrow + ((lhi ^ e) << 4));
        bf16x8 v1 = *reinterpret_cast<const bf16x8*>(vrow + (((4 + lhi) ^ e) << 4));
#pragma unroll
        for (int mi = 0; mi < 2; ++mi) {
          O[mi][h4] = MFMA16(ap[mi][0], v0, O[mi][h4]);
          O[mi][h4] = MFMA16(ap[mi][1], v1, O[mi][h4]);
        }
      }
    }
    __syncthreads();   // drains vmcnt (staging) + lgkm; protects both buffers
  }

  // ---- epilogue: 1/l broadcast, store ctx
#pragma unroll
  for (int mi = 0; mi < 2; ++mi)
    if (lhi == 0) albuf[mi * 16 + l15] = 1.0f / lS[mi];
#pragma unroll
  for (int mi = 0; mi < 2; ++mi) {
    f32x4 il = *reinterpret_cast<const f32x4*>(albuf + mi * 16 + lhi * 4);
#pragma unroll
    for (int h4 = 0; h4 < 4; ++h4)
#pragma unroll
      for (int r = 0; r < 4; ++r) {
        int row = r0 + mi * 16 + lhi * 4 + r;
        ctx[(size_t)row * 1024 + h * 64 + h4 * 16 + l15] =
            (bf16_t)(O[mi][h4][r] * il[r]);
      }
  }
}

// ---------------------------------------------------------------- launch
extern "C" void kernel_launch(void* const* d_in, const int* in_sizes, int n_in,
                              void* d_out, int out_size, void* d_ws, size_t ws_size,
                              hipStream_t stream) {
  const float* x  = (const float*)d_in[0];
  const float* wq = (const float*)d_in[1];
  const float* wk = (const float*)d_in[2];
  const float* wv = (const float*)d_in[3];
  const float* wo = (const float*)d_in[4];
  float* out = (float*)d_out;

  char* ws = (char*)d_ws;
  size_t off = 0;
  auto alloc = [&](size_t b) {
    char* p = ws + off;
    off += (b + 255) & ~(size_t)255;
    return p;
  };
  bf16_t* xb   = (bf16_t*)alloc((size_t)4096 * 1024 * 2);
  bf16_t* wqkv = (bf16_t*)alloc((size_t)1536 * 1024 * 2);
  bf16_t* wob  = (bf16_t*)alloc((size_t)1024 * 1024 * 2);
  bf16_t* qkv  = (bf16_t*)alloc((size_t)4096 * 1536 * 2);
  bf16_t* vtb  = (bf16_t*)alloc((size_t)256 * 4096 * 2);
  bf16_t* ctx  = (bf16_t*)alloc((size_t)4096 * 1024 * 2);

  cvt_kernel<<<2048, 256, 0, stream>>>(x, xb, 4096 * 1024);
  cvt_kernel<<<512, 256, 0, stream>>>(wq, wqkv, 1024 * 1024);
  cvt_kernel<<<128, 256, 0, stream>>>(wk, wqkv + (size_t)1024 * 1024, 256 * 1024);
  cvt_kernel<<<128, 256, 0, stream>>>(wv, wqkv + (size_t)1280 * 1024, 256 * 1024);
  cvt_kernel<<<512, 256, 0, stream>>>(wo, wob, 1024 * 1024);

  gemm_bt<bf16_t><<<dim3(12, 32), 256, 0, stream>>>(xb, wqkv, qkv, 4096, 1536, 1024);
  transpose_v<<<dim3(64, 4), 256, 0, stream>>>(qkv, vtb);
  attn_kernel<<<dim3(32, 16), 256, 0, stream>>>(qkv, vtb, ctx);
  gemm_bt<float><<<dim3(8, 32), 256, 0, stream>>>(ctx, wob, out, 4096, 1024, 1024);
}

// Round 3
// 208.480 us; speedup vs baseline: 2.3895x; 1.2047x over previous
//
#include <hip/hip_runtime.h>

typedef __bf16 bf16_t;
typedef __bf16 bf16x8 __attribute__((ext_vector_type(8)));
typedef float  f32x4  __attribute__((ext_vector_type(4)));

#define MFMA16(a, b, c) __builtin_amdgcn_mfma_f32_16x16x32_bf16((a), (b), (c), 0, 0, 0)

__device__ __forceinline__ void gload_lds16(const void* g, void* l) {
  __builtin_amdgcn_global_load_lds((__attribute__((address_space(1))) void*)(g),
                                   (__attribute__((address_space(3))) void*)(l),
                                   16, 0, 0);
}

// ---------------------------------------------------------------- convert
__global__ __launch_bounds__(256) void cvt_kernel(const float* __restrict__ in,
                                                  bf16_t* __restrict__ out, int n) {
  int i = (blockIdx.x * 256 + threadIdx.x) * 8;
  if (i >= n) return;
  const float4* p = reinterpret_cast<const float4*>(in + i);
  float4 a = p[0], b = p[1];
  bf16x8 v;
  v[0] = (bf16_t)a.x; v[1] = (bf16_t)a.y; v[2] = (bf16_t)a.z; v[3] = (bf16_t)a.w;
  v[4] = (bf16_t)b.x; v[5] = (bf16_t)b.y; v[6] = (bf16_t)b.z; v[7] = (bf16_t)b.w;
  *reinterpret_cast<bf16x8*>(out + i) = v;
}

// ---------------------------------------------------------------- GEMM  C[M,N] = A[M,K] * B[N,K]^T
template <typename T>
__global__ __launch_bounds__(256) void gemm_bt(const bf16_t* __restrict__ A,
                                               const bf16_t* __restrict__ B,
                                               T* __restrict__ C,
                                               int M, int N, int K) {
  constexpr int BK = 64;
  int tid  = threadIdx.x;
  int lane = tid & 63, w = tid >> 6;
  int wr = w >> 1, wc = w & 1;
  int l15 = lane & 15, lhi = lane >> 4;
  int row0 = blockIdx.y * 128, col0 = blockIdx.x * 128;

  __shared__ alignas(16) char smem[128 * BK * 2 * 2];
  char* sA = smem;
  char* sB = smem + 128 * BK * 2;

  f32x4 acc[4][4] = {};

  for (int k0 = 0; k0 < K; k0 += BK) {
#pragma unroll
    for (int i = 0; i < 4; ++i) {
      int c = i * 256 + tid;
      int r = c >> 3, kc = c & 7;
      int kk = k0 + ((kc ^ (r & 7)) << 3);
      gload_lds16(A + (size_t)(row0 + r) * K + kk, sA + c * 16);
      gload_lds16(B + (size_t)(col0 + r) * K + kk, sB + c * 16);
    }
    __syncthreads();
#pragma unroll
    for (int s = 0; s < 2; ++s) {
      bf16x8 af[4], bfr[4];
#pragma unroll
      for (int mi = 0; mi < 4; ++mi) {
        int r = wr * 64 + mi * 16 + l15;
        af[mi] = *reinterpret_cast<const bf16x8*>(
            sA + r * 128 + (((s * 4 + lhi) ^ (r & 7)) << 4));
      }
#pragma unroll
      for (int nj = 0; nj < 4; ++nj) {
        int r = wc * 64 + nj * 16 + l15;
        bfr[nj] = *reinterpret_cast<const bf16x8*>(
            sB + r * 128 + (((s * 4 + lhi) ^ (r & 7)) << 4));
      }
#pragma unroll
      for (int mi = 0; mi < 4; ++mi)
#pragma unroll
        for (int nj = 0; nj < 4; ++nj)
          acc[mi][nj] = MFMA16(af[mi], bfr[nj], acc[mi][nj]);
    }
    __syncthreads();
  }

#pragma unroll
  for (int mi = 0; mi < 4; ++mi)
#pragma unroll
    for (int nj = 0; nj < 4; ++nj)
#pragma unroll
      for (int r2 = 0; r2 < 4; ++r2) {
        int row = row0 + wr * 64 + mi * 16 + lhi * 4 + r2;
        int col = col0 + wc * 64 + nj * 16 + l15;
        C[(size_t)row * N + col] = (T)acc[mi][nj][r2];
      }
}

// ---------------------------------------------------------------- V transpose: qkv V-part -> Vt[256][4096]
__global__ __launch_bounds__(256) void transpose_v(const bf16_t* __restrict__ qkv,
                                                   bf16_t* __restrict__ vt) {
  __shared__ bf16_t tile[64][65];
  int t = threadIdx.x;
  int c = t & 63, r4 = t >> 6;
  int sb = blockIdx.x * 64, hb = blockIdx.y * 64;
#pragma unroll
  for (int i = 0; i < 16; ++i) {
    int r = i * 4 + r4;
    tile[r][c] = qkv[(size_t)(sb + r) * 1536 + 1280 + hb + c];
  }
  __syncthreads();
#pragma unroll
  for (int i = 0; i < 16; ++i) {
    int r = i * 4 + r4;
    vt[(size_t)(hb + r) * 4096 + sb + c] = tile[c][r];
  }
}

// ---------------------------------------------------------------- K repack: qkv K-part -> kp[4][4096][64]
__global__ __launch_bounds__(256) void repack_k(const bf16_t* __restrict__ qkv,
                                                bf16_t* __restrict__ kp) {
  int t = blockIdx.x * 256 + threadIdx.x;   // 131072 threads, 16B each
  int d8 = t & 7;
  int s  = (t >> 3) & 4095;
  int g  = t >> 15;
  bf16x8 v = *reinterpret_cast<const bf16x8*>(
      qkv + (size_t)s * 1536 + 1024 + g * 64 + d8 * 8);
  *reinterpret_cast<bf16x8*>(kp + ((size_t)g * 4096 + s) * 64 + d8 * 8) = v;
}

// ---------------------------------------------------------------- flash attention (causal GQA)
// 1 wave per block, 32 q-rows x 1 head; zero barriers; direct-L2 K/V reads;
// static-max softmax; LPT grid order. grid = 2048 blocks x 64 threads.
__global__ __launch_bounds__(64) void attn_kernel(const bf16_t* __restrict__ qkv,
                                                  const bf16_t* __restrict__ kp,
                                                  const bf16_t* __restrict__ vt,
                                                  bf16_t* __restrict__ ctx) {
  int lane = threadIdx.x & 63;
  int l15 = lane & 15, lhi = lane >> 4;
  int e = l15 & 7;
  int bid = blockIdx.x;
  int h = bid & 15;
  int tile = 127 - (bid >> 4);     // LPT: heaviest q-tiles first
  int g = h >> 2;
  int r0 = tile * 32;
  int nsteps = (tile >> 1) + 1;

  __shared__ alignas(16) char pbuf[4096];   // wave-private P [32][64] bf16, swizzled
  __shared__ float albuf[32];

  const bf16_t* kbase = kp + (size_t)g * 4096 * 64;
  const bf16_t* vbase = vt + (size_t)g * 64 * 4096;

  // Q fragments (MFMA B-operand: col=qrow=l15, k-slice d=lhi*8)
  bf16x8 qf[2][2];
#pragma unroll
  for (int mi = 0; mi < 2; ++mi)
#pragma unroll
    for (int ks = 0; ks < 2; ++ks)
      qf[mi][ks] = *reinterpret_cast<const bf16x8*>(
          qkv + (size_t)(r0 + mi * 16 + l15) * 1536 + h * 64 + ks * 32 + lhi * 8);

  f32x4 O[2][4] = {};
  float lsum[2] = {0.f, 0.f};
  const float SC = 0.125f * 1.44269504f;
  const float MB = 17.3123404907f;   // 12 nats static max bias (log2 units)

  for (int step = 0; step < nsteps; ++step) {
    int j0 = step * 64;
    // ---- K and V fragments, direct from L2 (issue all loads up front)
    bf16x8 kf[4][2], vf[4][2];
#pragma unroll
    for (int nj = 0; nj < 4; ++nj) {
      const bf16_t* kr = kbase + (size_t)(j0 + nj * 16 + l15) * 64 + lhi * 8;
      kf[nj][0] = *reinterpret_cast<const bf16x8*>(kr);
      kf[nj][1] = *reinterpret_cast<const bf16x8*>(kr + 32);
    }
#pragma unroll
    for (int h4 = 0; h4 < 4; ++h4) {
      const bf16_t* vr = vbase + (size_t)(h4 * 16 + l15) * 4096 + j0 + lhi * 8;
      vf[h4][0] = *reinterpret_cast<const bf16x8*>(vr);
      vf[h4][1] = *reinterpret_cast<const bf16x8*>(vr + 32);
    }
    // ---- QK^T (swapped): st[nj][mi] key=nj*16+lhi*4+r, qrow=mi*16+l15
    f32x4 st[4][2];
#pragma unroll
    for (int nj = 0; nj < 4; ++nj)
#pragma unroll
      for (int mi = 0; mi < 2; ++mi) {
        f32x4 t = {0.f, 0.f, 0.f, 0.f};
        t = MFMA16(kf[nj][0], qf[mi][0], t);
        t = MFMA16(kf[nj][1], qf[mi][1], t);
        st[nj][mi] = t;
      }
    // ---- causal mask (boundary steps only)
    if (j0 + 64 > r0) {
#pragma unroll
      for (int nj = 0; nj < 4; ++nj)
#pragma unroll
        for (int mi = 0; mi < 2; ++mi)
#pragma unroll
          for (int r = 0; r < 4; ++r) {
            int key = j0 + nj * 16 + lhi * 4 + r;
            int qr  = r0 + mi * 16 + l15;
            if (key > qr) st[nj][mi][r] = -1e30f;
          }
    }
    // ---- static-max softmax: P = exp2(s*SC - MB); no max-reduce, no rescale
#pragma unroll
    for (int mi = 0; mi < 2; ++mi) {
      float ls = 0.f;
#pragma unroll
      for (int nj = 0; nj < 4; ++nj)
#pragma unroll
        for (int r = 0; r < 4; ++r) {
          float p = exp2f(st[nj][mi][r] * SC - MB);
          st[nj][mi][r] = p;
          ls += p;
        }
      lsum[mi] += ls;
    }
    // ---- P -> LDS (bf16, swizzled [qrow][key])
#pragma unroll
    for (int mi = 0; mi < 2; ++mi) {
      char* prow = pbuf + (mi * 16 + l15) * 128 + ((lhi & 1) << 3);
#pragma unroll
      for (int nj = 0; nj < 4; ++nj) {
        int sw = (nj * 2 + (lhi >> 1)) ^ e;
        union { bf16_t hh[2]; uint32_t u; } a, c;
        a.hh[0] = (bf16_t)st[nj][mi][0]; a.hh[1] = (bf16_t)st[nj][mi][1];
        c.hh[0] = (bf16_t)st[nj][mi][2]; c.hh[1] = (bf16_t)st[nj][mi][3];
        *reinterpret_cast<uint32_t*>(prow + sw * 16)     = a.u;
        *reinterpret_cast<uint32_t*>(prow + sw * 16 + 4) = c.u;
      }
    }
    // ---- PV: A = P (qrow=l15), B = V^T (hd=l15)
    bf16x8 ap[2][2];
#pragma unroll
    for (int mi = 0; mi < 2; ++mi)
#pragma unroll
      for (int ks = 0; ks < 2; ++ks)
        ap[mi][ks] = *reinterpret_cast<const bf16x8*>(
            pbuf + (mi * 16 + l15) * 128 + (((ks * 4 + lhi) ^ e) << 4));
#pragma unroll
    for (int h4 = 0; h4 < 4; ++h4)
#pragma unroll
      for (int mi = 0; mi < 2; ++mi) {
        O[mi][h4] = MFMA16(ap[mi][0], vf[h4][0], O[mi][h4]);
        O[mi][h4] = MFMA16(ap[mi][1], vf[h4][1], O[mi][h4]);
      }
  }

  // ---- epilogue: reduce l across the 4 lhi lanes, broadcast 1/l via LDS strip
#pragma unroll
  for (int mi = 0; mi < 2; ++mi) {
    float l = lsum[mi];
    l += __shfl_xor(l, 16);
    l += __shfl_xor(l, 32);
    if (lhi == 0) albuf[mi * 16 + l15] = 1.0f / l;
  }
#pragma unroll
  for (int mi = 0; mi < 2; ++mi) {
    f32x4 il = *reinterpret_cast<const f32x4*>(albuf + mi * 16 + lhi * 4);
#pragma unroll
    for (int h4 = 0; h4 < 4; ++h4)
#pragma unroll
      for (int r = 0; r < 4; ++r) {
        int row = r0 + mi * 16 + lhi * 4 + r;
        ctx[(size_t)row * 1024 + h * 64 + h4 * 16 + l15] =
            (bf16_t)(O[mi][h4][r] * il[r]);
      }
  }
}

// ---------------------------------------------------------------- launch
extern "C" void kernel_launch(void* const* d_in, const int* in_sizes, int n_in,
                              void* d_out, int out_size, void* d_ws, size_t ws_size,
                              hipStream_t stream) {
  const float* x  = (const float*)d_in[0];
  const float* wq = (const float*)d_in[1];
  const float* wk = (const float*)d_in[2];
  const float* wv = (const float*)d_in[3];
  const float* wo = (const float*)d_in[4];
  float* out = (float*)d_out;

  char* ws = (char*)d_ws;
  size_t off = 0;
  auto alloc = [&](size_t b) {
    char* p = ws + off;
    off += (b + 255) & ~(size_t)255;
    return p;
  };
  bf16_t* xb   = (bf16_t*)alloc((size_t)4096 * 1024 * 2);
  bf16_t* wqkv = (bf16_t*)alloc((size_t)1536 * 1024 * 2);
  bf16_t* wob  = (bf16_t*)alloc((size_t)1024 * 1024 * 2);
  bf16_t* qkv  = (bf16_t*)alloc((size_t)4096 * 1536 * 2);
  bf16_t* vtb  = (bf16_t*)alloc((size_t)256 * 4096 * 2);
  bf16_t* kpb  = (bf16_t*)alloc((size_t)4 * 4096 * 64 * 2);
  bf16_t* ctx  = (bf16_t*)alloc((size_t)4096 * 1024 * 2);

  cvt_kernel<<<2048, 256, 0, stream>>>(x, xb, 4096 * 1024);
  cvt_kernel<<<512, 256, 0, stream>>>(wq, wqkv, 1024 * 1024);
  cvt_kernel<<<128, 256, 0, stream>>>(wk, wqkv + (size_t)1024 * 1024, 256 * 1024);
  cvt_kernel<<<128, 256, 0, stream>>>(wv, wqkv + (size_t)1280 * 1024, 256 * 1024);
  cvt_kernel<<<512, 256, 0, stream>>>(wo, wob, 1024 * 1024);

  gemm_bt<bf16_t><<<dim3(12, 32), 256, 0, stream>>>(xb, wqkv, qkv, 4096, 1536, 1024);
  transpose_v<<<dim3(64, 4), 256, 0, stream>>>(qkv, vtb);
  repack_k<<<512, 256, 0, stream>>>(qkv, kpb);
  attn_kernel<<<2048, 64, 0, stream>>>(qkv, kpb, vtb, ctx);
  gemm_bt<float><<<dim3(8, 32), 256, 0, stream>>>(ctx, wob, out, 4096, 1024, 1024);
}

// Round 4
// 193.411 us; speedup vs baseline: 2.5757x; 1.0779x over previous
//
#include <hip/hip_runtime.h>

typedef __bf16 bf16_t;
typedef __bf16 bf16x8 __attribute__((ext_vector_type(8)));
typedef float  f32x4  __attribute__((ext_vector_type(4)));

#define MFMA16(a, b, c) __builtin_amdgcn_mfma_f32_16x16x32_bf16((a), (b), (c), 0, 0, 0)

__device__ __forceinline__ void gload_lds16(const void* g, void* l) {
  __builtin_amdgcn_global_load_lds((__attribute__((address_space(1))) void*)(g),
                                   (__attribute__((address_space(3))) void*)(l),
                                   16, 0, 0);
}

// ---------------------------------------------------------------- convert
__global__ __launch_bounds__(256) void cvt_kernel(const float* __restrict__ in,
                                                  bf16_t* __restrict__ out, int n) {
  int i = (blockIdx.x * 256 + threadIdx.x) * 8;
  if (i >= n) return;
  const float4* p = reinterpret_cast<const float4*>(in + i);
  float4 a = p[0], b = p[1];
  bf16x8 v;
  v[0] = (bf16_t)a.x; v[1] = (bf16_t)a.y; v[2] = (bf16_t)a.z; v[3] = (bf16_t)a.w;
  v[4] = (bf16_t)b.x; v[5] = (bf16_t)b.y; v[6] = (bf16_t)b.z; v[7] = (bf16_t)b.w;
  *reinterpret_cast<bf16x8*>(out + i) = v;
}

// ---------------------------------------------------------------- GEMM  C[M,N] = A[M,K] * B[N,K]^T
template <typename T>
__global__ __launch_bounds__(256) void gemm_bt(const bf16_t* __restrict__ A,
                                               const bf16_t* __restrict__ B,
                                               T* __restrict__ C,
                                               int M, int N, int K) {
  constexpr int BK = 64;
  int tid  = threadIdx.x;
  int lane = tid & 63, w = tid >> 6;
  int wr = w >> 1, wc = w & 1;
  int l15 = lane & 15, lhi = lane >> 4;
  int row0 = blockIdx.y * 128, col0 = blockIdx.x * 128;

  __shared__ alignas(16) char smem[128 * BK * 2 * 2];
  char* sA = smem;
  char* sB = smem + 128 * BK * 2;

  f32x4 acc[4][4] = {};

  for (int k0 = 0; k0 < K; k0 += BK) {
#pragma unroll
    for (int i = 0; i < 4; ++i) {
      int c = i * 256 + tid;
      int r = c >> 3, kc = c & 7;
      int kk = k0 + ((kc ^ (r & 7)) << 3);
      gload_lds16(A + (size_t)(row0 + r) * K + kk, sA + c * 16);
      gload_lds16(B + (size_t)(col0 + r) * K + kk, sB + c * 16);
    }
    __syncthreads();
#pragma unroll
    for (int s = 0; s < 2; ++s) {
      bf16x8 af[4], bfr[4];
#pragma unroll
      for (int mi = 0; mi < 4; ++mi) {
        int r = wr * 64 + mi * 16 + l15;
        af[mi] = *reinterpret_cast<const bf16x8*>(
            sA + r * 128 + (((s * 4 + lhi) ^ (r & 7)) << 4));
      }
#pragma unroll
      for (int nj = 0; nj < 4; ++nj) {
        int r = wc * 64 + nj * 16 + l15;
        bfr[nj] = *reinterpret_cast<const bf16x8*>(
            sB + r * 128 + (((s * 4 + lhi) ^ (r & 7)) << 4));
      }
#pragma unroll
      for (int mi = 0; mi < 4; ++mi)
#pragma unroll
        for (int nj = 0; nj < 4; ++nj)
          acc[mi][nj] = MFMA16(af[mi], bfr[nj], acc[mi][nj]);
    }
    __syncthreads();
  }

#pragma unroll
  for (int mi = 0; mi < 4; ++mi)
#pragma unroll
    for (int nj = 0; nj < 4; ++nj)
#pragma unroll
      for (int r2 = 0; r2 < 4; ++r2) {
        int row = row0 + wr * 64 + mi * 16 + lhi * 4 + r2;
        int col = col0 + wc * 64 + nj * 16 + l15;
        C[(size_t)row * N + col] = (T)acc[mi][nj][r2];
      }
}

// ---------------------------------------------------------------- V transpose: qkv V-part -> Vt[256][4096]
__global__ __launch_bounds__(256) void transpose_v(const bf16_t* __restrict__ qkv,
                                                   bf16_t* __restrict__ vt) {
  __shared__ bf16_t tile[64][65];
  int t = threadIdx.x;
  int c = t & 63, r4 = t >> 6;
  int sb = blockIdx.x * 64, hb = blockIdx.y * 64;
#pragma unroll
  for (int i = 0; i < 16; ++i) {
    int r = i * 4 + r4;
    tile[r][c] = qkv[(size_t)(sb + r) * 1536 + 1280 + hb + c];
  }
  __syncthreads();
#pragma unroll
  for (int i = 0; i < 16; ++i) {
    int r = i * 4 + r4;
    vt[(size_t)(hb + r) * 4096 + sb + c] = tile[c][r];
  }
}

// ---------------------------------------------------------------- K repack: qkv K-part -> kp[4][4096][64]
__global__ __launch_bounds__(256) void repack_k(const bf16_t* __restrict__ qkv,
                                                bf16_t* __restrict__ kp) {
  int t = blockIdx.x * 256 + threadIdx.x;
  int d8 = t & 7;
  int s  = (t >> 3) & 4095;
  int g  = t >> 15;
  bf16x8 v = *reinterpret_cast<const bf16x8*>(
      qkv + (size_t)s * 1536 + 1024 + g * 64 + d8 * 8);
  *reinterpret_cast<bf16x8*>(kp + ((size_t)g * 4096 + s) * 64 + d8 * 8) = v;
}

// ---------------------------------------------------------------- flash attention (causal GQA)
// Block = 4 waves, one (32-row tile, head) item; wave w does KV steps w,w+4,...
// (static-max softmax -> partials additive); no per-step barriers; LDS combine.
__global__ __launch_bounds__(256) void attn_kernel(const bf16_t* __restrict__ qkv,
                                                   const bf16_t* __restrict__ kp,
                                                   const bf16_t* __restrict__ vt,
                                                   bf16_t* __restrict__ ctx) {
  int tid = threadIdx.x, lane = tid & 63, w = tid >> 6;
  int l15 = lane & 15, lhi = lane >> 4;
  int e = l15 & 7;
  int bid = blockIdx.x;
  int h = bid & 15;
  int tile = 127 - (bid >> 4);     // LPT: heaviest q-tiles first
  int g = h >> 2;
  int r0 = tile * 32;
  int nsteps = (tile >> 1) + 1;

  // smem: [0,16K) = 4x wave-private P buffers; after last PV use, the front
  // 24K is reused as the f32 combine buffer. combL/albuf live past 24K.
  __shared__ alignas(16) char smem[24 * 1024 + 2048];
  char* pbuf = smem + w * 4096;
  float* combO = (float*)smem;                   // [3][64 lanes][32 f32] swizzled
  float* combL = (float*)(smem + 24 * 1024);     // [2][3*64]
  float* albuf = combL + 2 * 192;                // [32]

  const bf16_t* kbase = kp + (size_t)g * 4096 * 64;
  const bf16_t* vbase = vt + (size_t)g * 64 * 4096;

  // Q fragments (MFMA B-operand: col=qrow=l15, k-slice d=lhi*8)
  bf16x8 qf[2][2];
#pragma unroll
  for (int mi = 0; mi < 2; ++mi)
#pragma unroll
    for (int ks = 0; ks < 2; ++ks)
      qf[mi][ks] = *reinterpret_cast<const bf16x8*>(
          qkv + (size_t)(r0 + mi * 16 + l15) * 1536 + h * 64 + ks * 32 + lhi * 8);

  f32x4 O[2][4] = {};
  float lsum[2] = {0.f, 0.f};
  const float SC = 0.125f * 1.44269504f;
  const float MB = 17.3123404907f;   // 12-nat static max bias (log2 units)

  for (int step = w; step < nsteps; step += 4) {
    int j0 = step * 64;
    // ---- K and V fragments, direct from L2
    bf16x8 kf[4][2], vf[4][2];
#pragma unroll
    for (int nj = 0; nj < 4; ++nj) {
      const bf16_t* kr = kbase + (size_t)(j0 + nj * 16 + l15) * 64 + lhi * 8;
      kf[nj][0] = *reinterpret_cast<const bf16x8*>(kr);
      kf[nj][1] = *reinterpret_cast<const bf16x8*>(kr + 32);
    }
#pragma unroll
    for (int h4 = 0; h4 < 4; ++h4) {
      const bf16_t* vr = vbase + (size_t)(h4 * 16 + l15) * 4096 + j0 + lhi * 8;
      vf[h4][0] = *reinterpret_cast<const bf16x8*>(vr);
      vf[h4][1] = *reinterpret_cast<const bf16x8*>(vr + 32);
    }
    // ---- QK^T (swapped): st[nj][mi] key=nj*16+lhi*4+r, qrow=mi*16+l15
    f32x4 st[4][2];
#pragma unroll
    for (int nj = 0; nj < 4; ++nj)
#pragma unroll
      for (int mi = 0; mi < 2; ++mi) {
        f32x4 t = {0.f, 0.f, 0.f, 0.f};
        t = MFMA16(kf[nj][0], qf[mi][0], t);
        t = MFMA16(kf[nj][1], qf[mi][1], t);
        st[nj][mi] = t;
      }
    // ---- causal mask (boundary steps only)
    if (j0 + 64 > r0) {
#pragma unroll
      for (int nj = 0; nj < 4; ++nj)
#pragma unroll
        for (int mi = 0; mi < 2; ++mi)
#pragma unroll
          for (int r = 0; r < 4; ++r) {
            int key = j0 + nj * 16 + lhi * 4 + r;
            int qr  = r0 + mi * 16 + l15;
            if (key > qr) st[nj][mi][r] = -1e30f;
          }
    }
    // ---- static-max softmax: P = exp2(s*SC - MB)
#pragma unroll
    for (int mi = 0; mi < 2; ++mi) {
      float ls = 0.f;
#pragma unroll
      for (int nj = 0; nj < 4; ++nj)
#pragma unroll
        for (int r = 0; r < 4; ++r) {
          float p = exp2f(st[nj][mi][r] * SC - MB);
          st[nj][mi][r] = p;
          ls += p;
        }
      lsum[mi] += ls;
    }
    // ---- P -> LDS (bf16, swizzled [qrow][key], ds_write_b64)
#pragma unroll
    for (int mi = 0; mi < 2; ++mi) {
      char* prow = pbuf + (mi * 16 + l15) * 128 + ((lhi & 1) << 3);
#pragma unroll
      for (int nj = 0; nj < 4; ++nj) {
        int sw = (nj * 2 + (lhi >> 1)) ^ e;
        union { bf16_t hh[4]; uint64_t u; } a;
        a.hh[0] = (bf16_t)st[nj][mi][0]; a.hh[1] = (bf16_t)st[nj][mi][1];
        a.hh[2] = (bf16_t)st[nj][mi][2]; a.hh[3] = (bf16_t)st[nj][mi][3];
        *reinterpret_cast<uint64_t*>(prow + sw * 16) = a.u;
      }
    }
    // ---- PV: A = P (qrow=l15), B = V^T (hd=l15)
    bf16x8 ap[2][2];
#pragma unroll
    for (int mi = 0; mi < 2; ++mi)
#pragma unroll
      for (int ks = 0; ks < 2; ++ks)
        ap[mi][ks] = *reinterpret_cast<const bf16x8*>(
            pbuf + (mi * 16 + l15) * 128 + (((ks * 4 + lhi) ^ e) << 4));
#pragma unroll
    for (int h4 = 0; h4 < 4; ++h4)
#pragma unroll
      for (int mi = 0; mi < 2; ++mi) {
        O[mi][h4] = MFMA16(ap[mi][0], vf[h4][0], O[mi][h4]);
        O[mi][h4] = MFMA16(ap[mi][1], vf[h4][1], O[mi][h4]);
      }
  }

  // ---- combine partials across the 4 waves (P buffers are dead now)
  __syncthreads();
  if (w > 0) {
    float* ob = combO + ((w - 1) * 64 + lane) * 32;
#pragma unroll
    for (int mi = 0; mi < 2; ++mi)
#pragma unroll
      for (int h4 = 0; h4 < 4; ++h4)
        *reinterpret_cast<f32x4*>(ob + (((mi * 4 + h4) ^ e) << 2)) = O[mi][h4];
#pragma unroll
    for (int mi = 0; mi < 2; ++mi)
      combL[mi * 192 + (w - 1) * 64 + lane] = lsum[mi];
  }
  __syncthreads();
  if (w > 0) return;

#pragma unroll
  for (int p = 0; p < 3; ++p) {
    const float* ob = combO + (p * 64 + lane) * 32;
#pragma unroll
    for (int mi = 0; mi < 2; ++mi) {
#pragma unroll
      for (int h4 = 0; h4 < 4; ++h4)
        O[mi][h4] += *reinterpret_cast<const f32x4*>(ob + (((mi * 4 + h4) ^ e) << 2));
      lsum[mi] += combL[mi * 192 + p * 64 + lane];
    }
  }

  // ---- epilogue: reduce l across lhi groups, broadcast 1/l, store
#pragma unroll
  for (int mi = 0; mi < 2; ++mi) {
    float l = lsum[mi];
    l += __shfl_xor(l, 16);
    l += __shfl_xor(l, 32);
    if (lhi == 0) albuf[mi * 16 + l15] = 1.0f / l;
  }
#pragma unroll
  for (int mi = 0; mi < 2; ++mi) {
    f32x4 il = *reinterpret_cast<const f32x4*>(albuf + mi * 16 + lhi * 4);
#pragma unroll
    for (int h4 = 0; h4 < 4; ++h4)
#pragma unroll
      for (int r = 0; r < 4; ++r) {
        int row = r0 + mi * 16 + lhi * 4 + r;
        ctx[(size_t)row * 1024 + h * 64 + h4 * 16 + l15] =
            (bf16_t)(O[mi][h4][r] * il[r]);
      }
  }
}

// ---------------------------------------------------------------- launch
extern "C" void kernel_launch(void* const* d_in, const int* in_sizes, int n_in,
                              void* d_out, int out_size, void* d_ws, size_t ws_size,
                              hipStream_t stream) {
  const float* x  = (const float*)d_in[0];
  const float* wq = (const float*)d_in[1];
  const float* wk = (const float*)d_in[2];
  const float* wv = (const float*)d_in[3];
  const float* wo = (const float*)d_in[4];
  float* out = (float*)d_out;

  char* ws = (char*)d_ws;
  size_t off = 0;
  auto alloc = [&](size_t b) {
    char* p = ws + off;
    off += (b + 255) & ~(size_t)255;
    return p;
  };
  bf16_t* xb   = (bf16_t*)alloc((size_t)4096 * 1024 * 2);
  bf16_t* wqkv = (bf16_t*)alloc((size_t)1536 * 1024 * 2);
  bf16_t* wob  = (bf16_t*)alloc((size_t)1024 * 1024 * 2);
  bf16_t* qkv  = (bf16_t*)alloc((size_t)4096 * 1536 * 2);
  bf16_t* vtb  = (bf16_t*)alloc((size_t)256 * 4096 * 2);
  bf16_t* kpb  = (bf16_t*)alloc((size_t)4 * 4096 * 64 * 2);
  bf16_t* ctx  = (bf16_t*)alloc((size_t)4096 * 1024 * 2);

  cvt_kernel<<<2048, 256, 0, stream>>>(x, xb, 4096 * 1024);
  cvt_kernel<<<512, 256, 0, stream>>>(wq, wqkv, 1024 * 1024);
  cvt_kernel<<<128, 256, 0, stream>>>(wk, wqkv + (size_t)1024 * 1024, 256 * 1024);
  cvt_kernel<<<128, 256, 0, stream>>>(wv, wqkv + (size_t)1280 * 1024, 256 * 1024);
  cvt_kernel<<<512, 256, 0, stream>>>(wo, wob, 1024 * 1024);

  gemm_bt<bf16_t><<<dim3(12, 32), 256, 0, stream>>>(xb, wqkv, qkv, 4096, 1536, 1024);
  transpose_v<<<dim3(64, 4), 256, 0, stream>>>(qkv, vtb);
  repack_k<<<512, 256, 0, stream>>>(qkv, kpb);
  attn_kernel<<<2048, 256, 0, stream>>>(qkv, kpb, vtb, ctx);
  gemm_bt<float><<<dim3(8, 32), 256, 0, stream>>>(ctx, wob, out, 4096, 1024, 1024);
}

// Round 5
// 153.201 us; speedup vs baseline: 3.2517x; 1.2625x over previous
//
#include <hip/hip_runtime.h>

typedef __bf16 bf16_t;
typedef __bf16 bf16x8 __attribute__((ext_vector_type(8)));
typedef float  f32x4  __attribute__((ext_vector_type(4)));

#define MFMA16(a, b, c) __builtin_amdgcn_mfma_f32_16x16x32_bf16((a), (b), (c), 0, 0, 0)

__device__ __forceinline__ void gload_lds16(const void* g, void* l) {
  __builtin_amdgcn_global_load_lds((__attribute__((address_space(1))) void*)(g),
                                   (__attribute__((address_space(3))) void*)(l),
                                   16, 0, 0);
}

// ---------------------------------------------------------------- convert
__global__ __launch_bounds__(256) void cvt_kernel(const float* __restrict__ in,
                                                  bf16_t* __restrict__ out, int n) {
  int i = (blockIdx.x * 256 + threadIdx.x) * 8;
  if (i >= n) return;
  const float4* p = reinterpret_cast<const float4*>(in + i);
  float4 a = p[0], b = p[1];
  bf16x8 v;
  v[0] = (bf16_t)a.x; v[1] = (bf16_t)a.y; v[2] = (bf16_t)a.z; v[3] = (bf16_t)a.w;
  v[4] = (bf16_t)b.x; v[5] = (bf16_t)b.y; v[6] = (bf16_t)b.z; v[7] = (bf16_t)b.w;
  *reinterpret_cast<bf16x8*>(out + i) = v;
}

// ---------------------------------------------------------------- GEMM  C[M,N] = A[M,K] * B[N,K]^T
template <typename T>
__global__ __launch_bounds__(256) void gemm_bt(const bf16_t* __restrict__ A,
                                               const bf16_t* __restrict__ B,
                                               T* __restrict__ C,
                                               int M, int N, int K) {
  constexpr int BK = 64;
  int tid  = threadIdx.x;
  int lane = tid & 63, w = tid >> 6;
  int wr = w >> 1, wc = w & 1;
  int l15 = lane & 15, lhi = lane >> 4;
  int row0 = blockIdx.y * 128, col0 = blockIdx.x * 128;

  __shared__ alignas(16) char smem[128 * BK * 2 * 2];
  char* sA = smem;
  char* sB = smem + 128 * BK * 2;

  f32x4 acc[4][4] = {};

  for (int k0 = 0; k0 < K; k0 += BK) {
#pragma unroll
    for (int i = 0; i < 4; ++i) {
      int c = i * 256 + tid;
      int r = c >> 3, kc = c & 7;
      int kk = k0 + ((kc ^ (r & 7)) << 3);
      gload_lds16(A + (size_t)(row0 + r) * K + kk, sA + c * 16);
      gload_lds16(B + (size_t)(col0 + r) * K + kk, sB + c * 16);
    }
    __syncthreads();
#pragma unroll
    for (int s = 0; s < 2; ++s) {
      bf16x8 af[4], bfr[4];
#pragma unroll
      for (int mi = 0; mi < 4; ++mi) {
        int r = wr * 64 + mi * 16 + l15;
        af[mi] = *reinterpret_cast<const bf16x8*>(
            sA + r * 128 + (((s * 4 + lhi) ^ (r & 7)) << 4));
      }
#pragma unroll
      for (int nj = 0; nj < 4; ++nj) {
        int r = wc * 64 + nj * 16 + l15;
        bfr[nj] = *reinterpret_cast<const bf16x8*>(
            sB + r * 128 + (((s * 4 + lhi) ^ (r & 7)) << 4));
      }
#pragma unroll
      for (int mi = 0; mi < 4; ++mi)
#pragma unroll
        for (int nj = 0; nj < 4; ++nj)
          acc[mi][nj] = MFMA16(af[mi], bfr[nj], acc[mi][nj]);
    }
    __syncthreads();
  }

#pragma unroll
  for (int mi = 0; mi < 4; ++mi)
#pragma unroll
    for (int nj = 0; nj < 4; ++nj)
#pragma unroll
      for (int r2 = 0; r2 < 4; ++r2) {
        int row = row0 + wr * 64 + mi * 16 + lhi * 4 + r2;
        int col = col0 + wc * 64 + nj * 16 + l15;
        C[(size_t)row * N + col] = (T)acc[mi][nj][r2];
      }
}

// ---------------------------------------------------------------- V transpose: qkv V-part -> Vt[256][4096]
__global__ __launch_bounds__(256) void transpose_v(const bf16_t* __restrict__ qkv,
                                                   bf16_t* __restrict__ vt) {
  __shared__ bf16_t tile[64][65];
  int t = threadIdx.x;
  int c = t & 63, r4 = t >> 6;
  int sb = blockIdx.x * 64, hb = blockIdx.y * 64;
#pragma unroll
  for (int i = 0; i < 16; ++i) {
    int r = i * 4 + r4;
    tile[r][c] = qkv[(size_t)(sb + r) * 1536 + 1280 + hb + c];
  }
  __syncthreads();
#pragma unroll
  for (int i = 0; i < 16; ++i) {
    int r = i * 4 + r4;
    vt[(size_t)(hb + r) * 4096 + sb + c] = tile[c][r];
  }
}

// ---------------------------------------------------------------- K repack: qkv K-part -> kp[4][4096][64]
__global__ __launch_bounds__(256) void repack_k(const bf16_t* __restrict__ qkv,
                                                bf16_t* __restrict__ kp) {
  int t = blockIdx.x * 256 + threadIdx.x;
  int d8 = t & 7;
  int s  = (t >> 3) & 4095;
  int g  = t >> 15;
  bf16x8 v = *reinterpret_cast<const bf16x8*>(
      qkv + (size_t)s * 1536 + 1024 + g * 64 + d8 * 8);
  *reinterpret_cast<bf16x8*>(kp + ((size_t)g * 4096 + s) * 64 + d8 * 8) = v;
}

// ---------------------------------------------------------------- flash attention (causal GQA)
// Block = 4 waves, one (64-row tile, head) item; wave w does KV steps w,w+4,...
// barrier-free main loop (static-max softmax -> partials additive); LDS combine.
__global__ __launch_bounds__(256, 2) void attn_kernel(const bf16_t* __restrict__ qkv,
                                                      const bf16_t* __restrict__ kp,
                                                      const bf16_t* __restrict__ vt,
                                                      bf16_t* __restrict__ ctx) {
  int tid = threadIdx.x, lane = tid & 63, w = tid >> 6;
  int l15 = lane & 15, lhi = lane >> 4;
  int e = l15 & 7;
  int bid = blockIdx.x;
  int h = bid & 15;
  int tile = 63 - (bid >> 4);     // LPT: heaviest q-tiles first
  int g = h >> 2;
  int r0 = tile * 64;
  int nsteps = tile + 1;          // 64-key steps

  // smem: 4 wave-private P buffers [64][64] bf16 swizzled (8KB each = 32KB);
  // reused post-loop as the f32 combine buffer (2 x 16KB phases).
  __shared__ alignas(16) char smem[32 * 1024];
  __shared__ alignas(16) float lbuf[3 * 256];
  char* pbuf = smem + w * 8192;

  const bf16_t* kbase = kp + (size_t)g * 4096 * 64;
  const bf16_t* vbase = vt + (size_t)g * 64 * 4096;

  // Q fragments (MFMA B-operand: col=qrow=l15, k-slice d=lhi*8)
  bf16x8 qf[4][2];
#pragma unroll
  for (int mi = 0; mi < 4; ++mi)
#pragma unroll
    for (int ks = 0; ks < 2; ++ks)
      qf[mi][ks] = *reinterpret_cast<const bf16x8*>(
          qkv + (size_t)(r0 + mi * 16 + l15) * 1536 + h * 64 + ks * 32 + lhi * 8);

  f32x4 O[4][4] = {};
  float lsum[4] = {0.f, 0.f, 0.f, 0.f};
  const float SC = 0.125f * 1.44269504f;
  const float MB = 17.3123404907f;   // 12-nat static max bias (log2 units)

  for (int step = w; step < nsteps; step += 4) {
    int j0 = step * 64;
    // ---- K fragments, direct from L2
    bf16x8 kf[4][2];
#pragma unroll
    for (int nj = 0; nj < 4; ++nj) {
      const bf16_t* kr = kbase + (size_t)(j0 + nj * 16 + l15) * 64 + lhi * 8;
      kf[nj][0] = *reinterpret_cast<const bf16x8*>(kr);
      kf[nj][1] = *reinterpret_cast<const bf16x8*>(kr + 32);
    }
    // ---- QK^T (swapped): st[nj][mi] key=nj*16+lhi*4+r, qrow=mi*16+l15
    f32x4 st[4][4];
#pragma unroll
    for (int nj = 0; nj < 4; ++nj)
#pragma unroll
      for (int mi = 0; mi < 4; ++mi) {
        f32x4 t = {0.f, 0.f, 0.f, 0.f};
        t = MFMA16(kf[nj][0], qf[mi][0], t);
        t = MFMA16(kf[nj][1], qf[mi][1], t);
        st[nj][mi] = t;
      }
    // ---- causal mask (only the diagonal step: j0 == r0)
    if (j0 + 64 > r0) {
#pragma unroll
      for (int nj = 0; nj < 4; ++nj)
#pragma unroll
        for (int mi = 0; mi < 4; ++mi)
#pragma unroll
          for (int r = 0; r < 4; ++r) {
            int key = j0 + nj * 16 + lhi * 4 + r;
            int qr  = r0 + mi * 16 + l15;
            if (key > qr) st[nj][mi][r] = -1e30f;
          }
    }
    // ---- static-max softmax: P = exp2(s*SC - MB)
#pragma unroll
    for (int mi = 0; mi < 4; ++mi) {
      float ls = 0.f;
#pragma unroll
      for (int nj = 0; nj < 4; ++nj)
#pragma unroll
        for (int r = 0; r < 4; ++r) {
          float p = exp2f(st[nj][mi][r] * SC - MB);
          st[nj][mi][r] = p;
          ls += p;
        }
      lsum[mi] += ls;
    }
    // ---- P -> LDS (bf16, swizzled [qrow][key], ds_write_b64)
#pragma unroll
    for (int mi = 0; mi < 4; ++mi) {
      char* prow = pbuf + (mi * 16 + l15) * 128 + ((lhi & 1) << 3);
#pragma unroll
      for (int nj = 0; nj < 4; ++nj) {
        int sw = (nj * 2 + (lhi >> 1)) ^ e;
        union { bf16_t hh[4]; uint64_t u; } a;
        a.hh[0] = (bf16_t)st[nj][mi][0]; a.hh[1] = (bf16_t)st[nj][mi][1];
        a.hh[2] = (bf16_t)st[nj][mi][2]; a.hh[3] = (bf16_t)st[nj][mi][3];
        *reinterpret_cast<uint64_t*>(prow + sw * 16) = a.u;
      }
    }
    // ---- PV: A = P (qrow=l15), B = V^T (hd=l15)
    bf16x8 ap[4][2];
#pragma unroll
    for (int mi = 0; mi < 4; ++mi)
#pragma unroll
      for (int ks = 0; ks < 2; ++ks)
        ap[mi][ks] = *reinterpret_cast<const bf16x8*>(
            pbuf + (mi * 16 + l15) * 128 + (((ks * 4 + lhi) ^ e) << 4));
#pragma unroll
    for (int h4 = 0; h4 < 4; ++h4) {
      const bf16_t* vr = vbase + (size_t)(h4 * 16 + l15) * 4096 + j0 + lhi * 8;
      bf16x8 v0 = *reinterpret_cast<const bf16x8*>(vr);
      bf16x8 v1 = *reinterpret_cast<const bf16x8*>(vr + 32);
#pragma unroll
      for (int mi = 0; mi < 4; ++mi) {
        O[mi][h4] = MFMA16(ap[mi][0], v0, O[mi][h4]);
        O[mi][h4] = MFMA16(ap[mi][1], v1, O[mi][h4]);
      }
    }
  }

  // ---- combine partials across the 4 waves (pbuf dead; 2 phases, 16KB each)
  __syncthreads();
  if (w == 1 || w == 2) {
    float* ob = (float*)smem + (w - 1) * 4096 + lane * 64;
#pragma unroll
    for (int mi = 0; mi < 4; ++mi)
#pragma unroll
      for (int h4 = 0; h4 < 4; ++h4)
        *reinterpret_cast<f32x4*>(ob + (((mi * 4 + h4) ^ e) << 2)) = O[mi][h4];
  }
  if (w > 0) {
    f32x4 lv = {lsum[0], lsum[1], lsum[2], lsum[3]};
    *reinterpret_cast<f32x4*>(lbuf + (w - 1) * 256 + lane * 4) = lv;
  }
  __syncthreads();
  if (w == 0) {
#pragma unroll
    for (int p = 0; p < 2; ++p) {
      const float* ob = (const float*)smem + p * 4096 + lane * 64;
#pragma unroll
      for (int mi = 0; mi < 4; ++mi)
#pragma unroll
        for (int h4 = 0; h4 < 4; ++h4)
          O[mi][h4] += *reinterpret_cast<const f32x4*>(ob + (((mi * 4 + h4) ^ e) << 2));
    }
#pragma unroll
    for (int p = 0; p < 3; ++p) {
      f32x4 lv = *reinterpret_cast<const f32x4*>(lbuf + p * 256 + lane * 4);
#pragma unroll
      for (int mi = 0; mi < 4; ++mi) lsum[mi] += lv[mi];
    }
  }
  __syncthreads();
  if (w == 3) {
    float* ob = (float*)smem + lane * 64;
#pragma unroll
    for (int mi = 0; mi < 4; ++mi)
#pragma unroll
      for (int h4 = 0; h4 < 4; ++h4)
        *reinterpret_cast<f32x4*>(ob + (((mi * 4 + h4) ^ e) << 2)) = O[mi][h4];
  }
  __syncthreads();
  if (w != 0) return;
  {
    const float* ob = (const float*)smem + lane * 64;
#pragma unroll
    for (int mi = 0; mi < 4; ++mi)
#pragma unroll
      for (int h4 = 0; h4 < 4; ++h4)
        O[mi][h4] += *reinterpret_cast<const f32x4*>(ob + (((mi * 4 + h4) ^ e) << 2));
  }

  // ---- epilogue: reduce l across lhi groups, broadcast 1/l via strip, store
  float* ilbuf = lbuf;   // reuse (wave 0 only, in-wave ordering)
#pragma unroll
  for (int mi = 0; mi < 4; ++mi) {
    float l = lsum[mi];
    l += __shfl_xor(l, 16);
    l += __shfl_xor(l, 32);
    if (lhi == 0) ilbuf[mi * 16 + l15] = 1.0f / l;
  }
#pragma unroll
  for (int mi = 0; mi < 4; ++mi) {
    f32x4 il = *reinterpret_cast<const f32x4*>(ilbuf + mi * 16 + lhi * 4);
#pragma unroll
    for (int h4 = 0; h4 < 4; ++h4)
#pragma unroll
      for (int r = 0; r < 4; ++r) {
        int row = r0 + mi * 16 + lhi * 4 + r;
        ctx[(size_t)row * 1024 + h * 64 + h4 * 16 + l15] =
            (bf16_t)(O[mi][h4][r] * il[r]);
      }
  }
}

// ---------------------------------------------------------------- launch
extern "C" void kernel_launch(void* const* d_in, const int* in_sizes, int n_in,
                              void* d_out, int out_size, void* d_ws, size_t ws_size,
                              hipStream_t stream) {
  const float* x  = (const float*)d_in[0];
  const float* wq = (const float*)d_in[1];
  const float* wk = (const float*)d_in[2];
  const float* wv = (const float*)d_in[3];
  const float* wo = (const float*)d_in[4];
  float* out = (float*)d_out;

  char* ws = (char*)d_ws;
  size_t off = 0;
  auto alloc = [&](size_t b) {
    char* p = ws + off;
    off += (b + 255) & ~(size_t)255;
    return p;
  };
  bf16_t* xb   = (bf16_t*)alloc((size_t)4096 * 1024 * 2);
  bf16_t* wqkv = (bf16_t*)alloc((size_t)1536 * 1024 * 2);
  bf16_t* wob  = (bf16_t*)alloc((size_t)1024 * 1024 * 2);
  bf16_t* qkv  = (bf16_t*)alloc((size_t)4096 * 1536 * 2);
  bf16_t* vtb  = (bf16_t*)alloc((size_t)256 * 4096 * 2);
  bf16_t* kpb  = (bf16_t*)alloc((size_t)4 * 4096 * 64 * 2);
  bf16_t* ctx  = (bf16_t*)alloc((size_t)4096 * 1024 * 2);

  cvt_kernel<<<2048, 256, 0, stream>>>(x, xb, 4096 * 1024);
  cvt_kernel<<<512, 256, 0, stream>>>(wq, wqkv, 1024 * 1024);
  cvt_kernel<<<128, 256, 0, stream>>>(wk, wqkv + (size_t)1024 * 1024, 256 * 1024);
  cvt_kernel<<<128, 256, 0, stream>>>(wv, wqkv + (size_t)1280 * 1024, 256 * 1024);
  cvt_kernel<<<512, 256, 0, stream>>>(wo, wob, 1024 * 1024);

  gemm_bt<bf16_t><<<dim3(12, 32), 256, 0, stream>>>(xb, wqkv, qkv, 4096, 1536, 1024);
  transpose_v<<<dim3(64, 4), 256, 0, stream>>>(qkv, vtb);
  repack_k<<<512, 256, 0, stream>>>(qkv, kpb);
  attn_kernel<<<1024, 256, 0, stream>>>(qkv, kpb, vtb, ctx);
  gemm_bt<float><<<dim3(8, 32), 256, 0, stream>>>(ctx, wob, out, 4096, 1024, 1024);
}